// Round 2
// 414.513 us; speedup vs baseline: 1.1705x; 1.1705x over previous
//
#include <hip/hip_runtime.h>

typedef __bf16 bf16x8 __attribute__((ext_vector_type(8)));
typedef float f32x16 __attribute__((ext_vector_type(16)));
typedef unsigned int u32x4 __attribute__((ext_vector_type(4)));

#define NGROUP 8
#define DMODEL 256
#define DFF    1024
#define TTOT   131072
#define TGRP   (TTOT / NGROUP)   // 16384
#define MTILE  256               // tokens per block (8 waves x 32)
#define NCHUNK 32                // f-chunks of 32 (DFF/32)
// LDS map (96 KB static): two 48KB chunk buffers (double-buffered weights)
//   buf b at u32x4 offset b*3072:
//     [   0, 16K)  gate A-frags [ks(16)][lane(64)] x 16B
//     [ 16K, 32K)  up   A-frags
//     [ 32K, 48K)  down B-frags [ks2(2)][nb(8)][lane(64)] x 16B
// h never touches LDS: GEMM2's A-fragment == packed GEMM1 accumulator regs,
// made layout-consistent by permuting the f->k mapping inside the Wd prep.

__device__ __forceinline__ unsigned int f2bf(float f) {
    unsigned int x = __builtin_bit_cast(unsigned int, f);
    return (x + 0x7fffu + ((x >> 16) & 1u)) >> 16;   // RNE
}
__device__ __forceinline__ unsigned int pack2(float lo, float hi) {
    return f2bf(lo) | (f2bf(hi) << 16);
}
__device__ __forceinline__ unsigned int cvtpk(float lo, float hi) {
    unsigned int r;
    asm("v_cvt_pk_bf16_f32 %0, %1, %2" : "=v"(r) : "v"(lo), "v"(hi));  // RNE, same as pack2
    return r;
}

__device__ __forceinline__ void g2l(const void* g, void* l) {
    __builtin_amdgcn_global_load_lds(
        (const __attribute__((address_space(1))) unsigned int*)g,
        (__attribute__((address_space(3))) unsigned int*)l, 16, 0, 0);
}

// ---------------- prep: all weights -> per-(group,chunk) 48KB frag blocks ----------------
// Per (g,c): 48 frag-groups of [64 lanes x 16B]:
//   fid 0..15  : gate A-frag, ks=fid      W[d=ks*16+q*8+j][f=c*32+l31]
//   fid 16..31 : up   A-frag, ks=fid-16
//   fid 32..47 : down B-frag, ks2=(fid-32)>>3, nb=(fid-32)&7
//     k-axis PERMUTED to match packed-accumulator A-frags:
//     B[k=q*8+j] = Wd[F = c*32 + ks2*16 + q*4 + (j&3) + 8*(j>>2)][col=nb*32+l31]
__global__ void k_prep_w(const float* __restrict__ wg, const float* __restrict__ wu,
                         const float* __restrict__ wd, u32x4* __restrict__ out) {
    int t = blockIdx.x * 256 + threadIdx.x;   // 786432 total
    int lane = t & 63;
    int q = lane >> 5, l31 = lane & 31;
    int fg = t >> 6;
    int fid = fg % 48;
    int gc  = fg / 48;
    int c = gc & 31, g = gc >> 5;
    u32x4 v;
    if (fid < 32) {
        const float* w = (fid < 16) ? wg : wu;
        int ks = fid & 15;
        const float* src = w + (size_t)(g * 256 + ks * 16 + q * 8) * 1024 + c * 32 + l31;
        v = u32x4{ pack2(src[0],        src[1024]),
                   pack2(src[2 * 1024], src[3 * 1024]),
                   pack2(src[4 * 1024], src[5 * 1024]),
                   pack2(src[6 * 1024], src[7 * 1024]) };
    } else {
        int idx = fid - 32;
        int ks2 = idx >> 3, nb = idx & 7;
        // rows f = base + {0,1,2,3, 8,9,10,11}  (permuted k-axis)
        const float* src = wd + (size_t)(g * 1024 + c * 32 + ks2 * 16 + q * 4) * 256 + nb * 32 + l31;
        v = u32x4{ pack2(src[0 * 256],  src[1 * 256]),
                   pack2(src[2 * 256],  src[3 * 256]),
                   pack2(src[8 * 256],  src[9 * 256]),
                   pack2(src[10 * 256], src[11 * 256]) };
    }
    out[t] = v;
}

// ---------------- main fused grouped-GLU ----------------
__global__ __launch_bounds__(512, 2)
void k_glu(const float* __restrict__ x,      // fp32 x row-major [T][256]
           const u32x4* __restrict__ wcomb,  // [g][c][48 frag-groups][64 lanes]
           float* __restrict__ y) {
    __shared__ u32x4 smem[6144];   // 96 KB: two 48KB buffers

    const int tid  = threadIdx.x;
    const int lane = tid & 63;
    const int w    = tid >> 6;      // wave 0..7 = token-32 block
    const int q    = lane >> 5;
    const int l31  = lane & 31;

    // XCD swizzle: group = blockIdx & 7 so each XCD's L2 holds one group's weights
    const int g    = blockIdx.x & 7;
    const int m0   = g * TGRP + (blockIdx.x >> 3) * MTILE;
    const int tok  = m0 + w * 32 + l31;

    const u32x4* wcg = wcomb + (size_t)(g * 32) * 3072;

    // ---- prologue: stage chunk 0 into buf 0 (async), then build x B-frags from fp32
    {
        #pragma unroll
        for (int i = 0; i < 6; ++i) {
            int off = i * 512 + w * 64;   // u32x4 index, wave-uniform LDS dest
            g2l(wcg + off + lane, smem + off);
        }
    }
    u32x4 xf[16];
    {
        const float* xrow = x + (size_t)tok * DMODEL + q * 8;
        #pragma unroll
        for (int ks = 0; ks < 16; ++ks) {
            float4 a = *(const float4*)(xrow + ks * 16);
            float4 b = *(const float4*)(xrow + ks * 16 + 4);
            xf[ks] = u32x4{ cvtpk(a.x, a.y), cvtpk(a.z, a.w),
                            cvtpk(b.x, b.y), cvtpk(b.z, b.w) };
        }
    }

    f32x16 acc[8];
    #pragma unroll
    for (int nb = 0; nb < 8; ++nb)
        #pragma unroll
        for (int i = 0; i < 16; ++i) acc[nb][i] = 0.0f;

    asm volatile("s_waitcnt vmcnt(0)" ::: "memory");   // chunk 0 staged
    __builtin_amdgcn_s_barrier();
    asm volatile("" ::: "memory");

    for (int c = 0; c < NCHUNK; ++c) {
        const u32x4* sb = smem + (c & 1) * 3072;

        // ---- prefetch chunk c+1 into the other buffer; counted vmcnt (never 0 in-loop)
        if (c + 1 < NCHUNK) {
            u32x4* db = smem + ((c + 1) & 1) * 3072;
            const u32x4* gsrc = wcg + (size_t)(c + 1) * 3072;
            #pragma unroll
            for (int i = 0; i < 6; ++i) {
                int off = i * 512 + w * 64;
                g2l(gsrc + off + lane, db + off);
            }
            asm volatile("s_waitcnt vmcnt(6)" ::: "memory");  // chunk c landed; c+1 in flight
        } else {
            asm volatile("s_waitcnt vmcnt(0)" ::: "memory");
        }
        __builtin_amdgcn_s_barrier();   // all waves' chunk-c staging visible
        asm volatile("" ::: "memory");

        // ---- GEMM1: z^T (32f x 32tok) over K=256, weights from LDS, x from regs
        f32x16 zg, zu;
        #pragma unroll
        for (int i = 0; i < 16; ++i) { zg[i] = 0.0f; zu[i] = 0.0f; }
        __builtin_amdgcn_s_setprio(1);
        #pragma unroll
        for (int ks = 0; ks < 16; ++ks) {
            const u32x4 a1 = sb[ks * 64 + lane];          // gate
            const u32x4 a2 = sb[1024 + ks * 64 + lane];   // up
            zg = __builtin_amdgcn_mfma_f32_32x32x16_bf16(
                     __builtin_bit_cast(bf16x8, a1),
                     __builtin_bit_cast(bf16x8, xf[ks]), zg, 0, 0, 0);
            zu = __builtin_amdgcn_mfma_f32_32x32x16_bf16(
                     __builtin_bit_cast(bf16x8, a2),
                     __builtin_bit_cast(bf16x8, xf[ks]), zu, 0, 0, 0);
        }
        __builtin_amdgcn_s_setprio(0);

        // ---- act: h = silu(zg)*zu, packed in-register (A-frag == natural reg order)
        float hv[16];
        #pragma unroll
        for (int i = 0; i < 16; ++i) {
            const float gv = zg[i];
            const float s  = __builtin_amdgcn_rcpf(1.0f + __expf(-gv));
            hv[i] = gv * s * zu[i];
        }
        const u32x4 ha0 = u32x4{ cvtpk(hv[0], hv[1]),   cvtpk(hv[2], hv[3]),
                                 cvtpk(hv[4], hv[5]),   cvtpk(hv[6], hv[7]) };
        const u32x4 ha1 = u32x4{ cvtpk(hv[8], hv[9]),   cvtpk(hv[10], hv[11]),
                                 cvtpk(hv[12], hv[13]), cvtpk(hv[14], hv[15]) };
        const bf16x8 A0 = __builtin_bit_cast(bf16x8, ha0);
        const bf16x8 A1 = __builtin_bit_cast(bf16x8, ha1);

        // ---- GEMM2: acc += h(32tok x 32f) * Wd(32f x 256), Wd k-permuted at prep
        __builtin_amdgcn_s_setprio(1);
        #pragma unroll
        for (int nb = 0; nb < 8; ++nb) {
            acc[nb] = __builtin_amdgcn_mfma_f32_32x32x16_bf16(
                          A0, __builtin_bit_cast(bf16x8, sb[2048 + nb * 64 + lane]),
                          acc[nb], 0, 0, 0);
        }
        #pragma unroll
        for (int nb = 0; nb < 8; ++nb) {
            acc[nb] = __builtin_amdgcn_mfma_f32_32x32x16_bf16(
                          A1, __builtin_bit_cast(bf16x8, sb[2048 + (8 + nb) * 64 + lane]),
                          acc[nb], 0, 0, 0);
        }
        __builtin_amdgcn_s_setprio(0);

        asm volatile("" ::: "memory");
        __builtin_amdgcn_s_barrier();   // all waves done reading sb before it is restaged
    }

    // epilogue: C layout -> y fp32
    float* yp = y + (size_t)(m0 + w * 32) * DMODEL;
    #pragma unroll
    for (int nb = 0; nb < 8; ++nb) {
        const int col = nb * 32 + l31;
        #pragma unroll
        for (int r = 0; r < 16; ++r) {
            const int row = (r & 3) + (r >> 2) * 8 + q * 4;
            yp[(size_t)row * DMODEL + col] = acc[nb][r];
        }
    }
}

extern "C" void kernel_launch(void* const* d_in, const int* in_sizes, int n_in,
                              void* d_out, int out_size, void* d_ws, size_t ws_size,
                              hipStream_t stream) {
    const float* x  = (const float*)d_in[0];
    const float* wg = (const float*)d_in[1];
    const float* wu = (const float*)d_in[2];
    const float* wd = (const float*)d_in[3];
    float* y = (float*)d_out;

    // ws: wcomb only (12.6 MB); x is consumed fp32 directly by k_glu
    u32x4* wcomb = (u32x4*)d_ws;   // 8*32*48*64 = 786432 u32x4

    k_prep_w<<<dim3(3072), dim3(256), 0, stream>>>(wg, wu, wd, wcomb);
    k_glu<<<dim3(512), dim3(512), 0, stream>>>(x, wcomb, y);
}